// Round 1
// baseline (134.142 us; speedup 1.0000x reference)
//
#include <hip/hip_runtime.h>
#include <math.h>

#define TT 512
#define DD 512
#define NH 8
#define HD 64
#define SCALE 0.125f  // 1/sqrt(64)

// ---------------------------------------------------------------------------
// Kernel 1: QKV projection.  P[o,t] = sum_d W[o,d] * x[t,d]
// Output layout [o][t] (channel-major) so the attention kernel reads rows.
// grid (T/32, O/32, 3), block (16,16); 32x32 output tile, 2x2 per thread.
// ---------------------------------------------------------------------------
__global__ __launch_bounds__(256) void proj_kernel(
    const float* __restrict__ x,
    const float* __restrict__ Wq,
    const float* __restrict__ Wk,
    const float* __restrict__ Wv,
    float* __restrict__ qp, float* __restrict__ kp, float* __restrict__ vp)
{
    const float* W;
    float* out;
    if (blockIdx.z == 0)      { W = Wq; out = qp; }
    else if (blockIdx.z == 1) { W = Wk; out = kp; }
    else                      { W = Wv; out = vp; }

    __shared__ float Ws[32][33];  // [o_local][d_local]
    __shared__ float Xs[32][33];  // [t_local][d_local]

    const int t0 = blockIdx.x * 32;
    const int o0 = blockIdx.y * 32;
    const int tx = threadIdx.x, ty = threadIdx.y;      // 16x16
    const int tid = ty * 16 + tx;
    const int lr  = tid / 8;          // 0..31 row for loading
    const int lc4 = (tid % 8) * 4;    // 0..28 col base (float4)

    float c00 = 0.f, c01 = 0.f, c10 = 0.f, c11 = 0.f;

    for (int d0 = 0; d0 < DD; d0 += 32) {
        float4 w4 = *(const float4*)&W[(o0 + lr) * DD + d0 + lc4];
        Ws[lr][lc4 + 0] = w4.x; Ws[lr][lc4 + 1] = w4.y;
        Ws[lr][lc4 + 2] = w4.z; Ws[lr][lc4 + 3] = w4.w;
        float4 x4 = *(const float4*)&x[(t0 + lr) * DD + d0 + lc4];
        Xs[lr][lc4 + 0] = x4.x; Xs[lr][lc4 + 1] = x4.y;
        Xs[lr][lc4 + 2] = x4.z; Xs[lr][lc4 + 3] = x4.w;
        __syncthreads();
        #pragma unroll
        for (int kk = 0; kk < 32; ++kk) {
            float a0 = Ws[ty * 2 + 0][kk];
            float a1 = Ws[ty * 2 + 1][kk];
            float b0 = Xs[tx * 2 + 0][kk];
            float b1 = Xs[tx * 2 + 1][kk];
            c00 = fmaf(a0, b0, c00); c01 = fmaf(a0, b1, c01);
            c10 = fmaf(a1, b0, c10); c11 = fmaf(a1, b1, c11);
        }
        __syncthreads();
    }
    const int o = o0 + ty * 2, t = t0 + tx * 2;
    out[(o + 0) * TT + t + 0] = c00;
    out[(o + 0) * TT + t + 1] = c01;
    out[(o + 1) * TT + t + 0] = c10;
    out[(o + 1) * TT + t + 1] = c11;
}

// ---------------------------------------------------------------------------
// Kernel 2: RoPE, in place on q and k.
// rotate_half splits the HEADS axis: out[h] = (h<4) ? -x[h+4] : x[h-4].
// Each thread owns one (low-head h in 0..3, c, t) pair and writes BOTH the
// low-head and high-head rotated values -> race-free in-place update.
// ---------------------------------------------------------------------------
__global__ __launch_bounds__(256) void rope_kernel(
    float* __restrict__ q, float* __restrict__ k)
{
    int idx = blockIdx.x * blockDim.x + threadIdx.x;  // 0 .. 4*HD*T-1
    if (idx >= 4 * HD * TT) return;
    const int t = idx & (TT - 1);
    const int c = (idx >> 9) & (HD - 1);
    const int h = idx >> 15;          // 0..3
    const int f = c & 31;             // freq index (emb = concat([freqs,freqs]))

    const float inv_freq = powf(10000.0f, -(float)f * (1.0f / 32.0f));
    const float ang = (float)t * inv_freq;
    float sn, cs;
    sincosf(ang, &sn, &cs);

    const int o_lo = (h)     * HD + c;   // head h   (gets -partner*sin)
    const int o_hi = (h + 4) * HD + c;   // head h+4 (gets +partner*sin)

    const float qlo = q[o_lo * TT + t], qhi = q[o_hi * TT + t];
    q[o_lo * TT + t] = qlo * cs - qhi * sn;
    q[o_hi * TT + t] = qhi * cs + qlo * sn;

    const float klo = k[o_lo * TT + t], khi = k[o_hi * TT + t];
    k[o_lo * TT + t] = klo * cs - khi * sn;
    k[o_hi * TT + t] = khi * cs + klo * sn;
}

// ---------------------------------------------------------------------------
// Kernel 3: per-channel scalar causal attention.
// s_j = q_i * a_j with a_j = k_j*scale  =>  rowmax = q_i>=0 ? q_i*pmax : q_i*pmin
// where pmax/pmin are inclusive prefix max/min of a (9-step scan in LDS).
// One block per channel (512), one thread per query position (512).
// ---------------------------------------------------------------------------
__global__ __launch_bounds__(512) void attn_kernel(
    const float* __restrict__ q, const float* __restrict__ k,
    const float* __restrict__ v, float* __restrict__ out)
{
    const int ch = blockIdx.x;
    const int i  = threadIdx.x;

    __shared__ float a[TT];
    __shared__ float vv[TT];
    __shared__ float pmx[TT];
    __shared__ float pmn[TT];

    const float av = k[ch * TT + i] * SCALE;
    a[i]  = av;
    vv[i] = v[ch * TT + i];
    pmx[i] = av;
    pmn[i] = av;
    __syncthreads();

    // inclusive prefix max/min (Hillis-Steele)
    float mx = av, mn = av;
    for (int off = 1; off < TT; off <<= 1) {
        float omx = (i >= off) ? pmx[i - off] : -INFINITY;
        float omn = (i >= off) ? pmn[i - off] :  INFINITY;
        __syncthreads();
        mx = fmaxf(mx, omx);
        mn = fminf(mn, omn);
        pmx[i] = mx;
        pmn[i] = mn;
        __syncthreads();
    }

    const float qi = q[ch * TT + i];
    const float m  = (qi >= 0.f) ? qi * mx : qi * mn;  // max_{j<=i} qi*a_j

    float l = 0.f, acc = 0.f;
    for (int j = 0; j <= i; ++j) {
        float e = __expf(fmaf(qi, a[j], -m));
        l   += e;
        acc  = fmaf(e, vv[j], acc);
    }
    out[ch * TT + i] = acc / l;
}

// ---------------------------------------------------------------------------
// Kernel 4: output projection.  out[t,o] = sum_d Wo[o,d] * A[d,t]
// A layout [d][t] (what attn_kernel wrote). Output row-major [t][o].
// ---------------------------------------------------------------------------
__global__ __launch_bounds__(256) void outproj_kernel(
    const float* __restrict__ Wo, const float* __restrict__ A,
    float* __restrict__ out)
{
    __shared__ float Ws[32][33];  // [o_local][d_local]
    __shared__ float As[32][33];  // [d_local][t_local]

    const int t0 = blockIdx.x * 32;
    const int o0 = blockIdx.y * 32;
    const int tx = threadIdx.x, ty = threadIdx.y;
    const int tid = ty * 16 + tx;
    const int lr  = tid / 8;
    const int lc4 = (tid % 8) * 4;

    float c00 = 0.f, c01 = 0.f, c10 = 0.f, c11 = 0.f;

    for (int d0 = 0; d0 < DD; d0 += 32) {
        float4 w4 = *(const float4*)&Wo[(o0 + lr) * DD + d0 + lc4];
        Ws[lr][lc4 + 0] = w4.x; Ws[lr][lc4 + 1] = w4.y;
        Ws[lr][lc4 + 2] = w4.z; Ws[lr][lc4 + 3] = w4.w;
        float4 a4 = *(const float4*)&A[(d0 + lr) * TT + t0 + lc4];
        As[lr][lc4 + 0] = a4.x; As[lr][lc4 + 1] = a4.y;
        As[lr][lc4 + 2] = a4.z; As[lr][lc4 + 3] = a4.w;
        __syncthreads();
        #pragma unroll
        for (int kk = 0; kk < 32; ++kk) {
            float a0 = Ws[ty * 2 + 0][kk];
            float a1 = Ws[ty * 2 + 1][kk];
            float b0 = As[kk][tx * 2 + 0];
            float b1 = As[kk][tx * 2 + 1];
            c00 = fmaf(a0, b0, c00); c01 = fmaf(a0, b1, c01);
            c10 = fmaf(a1, b0, c10); c11 = fmaf(a1, b1, c11);
        }
        __syncthreads();
    }
    const int o = o0 + ty * 2, t = t0 + tx * 2;
    out[(t + 0) * DD + o + 0] = c00;
    out[(t + 1) * DD + o + 0] = c01;
    out[(t + 0) * DD + o + 1] = c10;
    out[(t + 1) * DD + o + 1] = c11;
}

// ---------------------------------------------------------------------------
extern "C" void kernel_launch(void* const* d_in, const int* in_sizes, int n_in,
                              void* d_out, int out_size, void* d_ws, size_t ws_size,
                              hipStream_t stream)
{
    const float* x  = (const float*)d_in[0];
    const float* Wq = (const float*)d_in[1];
    const float* Wk = (const float*)d_in[2];
    const float* Wv = (const float*)d_in[3];
    const float* Wo = (const float*)d_in[4];
    float* out = (float*)d_out;

    float* ws = (float*)d_ws;
    float* qp = ws;                    // [512][512]  q (RoPE'd in place)
    float* kp = ws + 1 * DD * TT;      // [512][512]  k (RoPE'd in place)
    float* vp = ws + 2 * DD * TT;      // [512][512]  v
    float* ao = ws + 3 * DD * TT;      // [512][512]  attention output [d][t]

    dim3 blk(16, 16);
    proj_kernel<<<dim3(TT / 32, DD / 32, 3), blk, 0, stream>>>(x, Wq, Wk, Wv, qp, kp, vp);
    rope_kernel<<<(4 * HD * TT) / 256, 256, 0, stream>>>(qp, kp);
    attn_kernel<<<DD, TT, 0, stream>>>(qp, kp, vp, ao);
    outproj_kernel<<<dim3(TT / 32, DD / 32), blk, 0, stream>>>(Wo, ao, out);
}